// Round 1
// baseline (135.998 us; speedup 1.0000x reference)
//
#include <hip/hip_runtime.h>
#include <hip/hip_bf16.h>

#define N_TOT 8192
#define DIM 256
#define HALF_B 4096
#define CHUNKS 16
#define COLS_PER_CHUNK (N_TOT / CHUNKS)      // 512
#define ROWS_PER_WAVE 32
#define ROWS_PER_BLOCK 128                   // 4 waves * 32 rows
#define ROW_BLOCKS (N_TOT / ROWS_PER_BLOCK)  // 64

typedef __attribute__((ext_vector_type(8))) short bfrag;   // 8 bf16 = 4 VGPRs
typedef __attribute__((ext_vector_type(4))) float facc;    // 4 f32 accum

static __device__ __forceinline__ unsigned short f2bf(float x) {
    __hip_bfloat16 h = __float2bfloat16(x);
    return __builtin_bit_cast(unsigned short, h);
}

// Kernel 1: row-normalize concat(z_i, z_j) -> zn bf16 [N_TOT][DIM]
__global__ __launch_bounds__(256) void norm_kernel(const float* __restrict__ zi,
                                                   const float* __restrict__ zj,
                                                   unsigned short* __restrict__ zn) {
    int row  = blockIdx.x * 4 + (threadIdx.x >> 6);
    int lane = threadIdx.x & 63;
    const float* src = (row < HALF_B) ? (zi + (size_t)row * DIM)
                                      : (zj + (size_t)(row - HALF_B) * DIM);
    float4 v = reinterpret_cast<const float4*>(src)[lane];
    float ss = v.x * v.x + v.y * v.y + v.z * v.z + v.w * v.w;
    #pragma unroll
    for (int off = 32; off; off >>= 1) ss += __shfl_xor(ss, off);
    float inv = 1.0f / fmaxf(sqrtf(ss), 1e-8f);
    ushort4 o;
    o.x = f2bf(v.x * inv);
    o.y = f2bf(v.y * inv);
    o.z = f2bf(v.z * inv);
    o.w = f2bf(v.w * inv);
    reinterpret_cast<ushort4*>(zn + (size_t)row * DIM)[lane] = o;
}

// Kernel 2: fused zn@zn^T (bf16 MFMA) + exp row-sum partials + pos extraction.
// Grid: (ROW_BLOCKS, CHUNKS). Block: 256 thr = 4 waves, wave owns 32 rows.
__global__ __launch_bounds__(256) void sim_kernel(const unsigned short* __restrict__ zn,
                                                  float* __restrict__ partial,
                                                  float* __restrict__ pos) {
    const int lane    = threadIdx.x & 63;
    const int wv      = threadIdx.x >> 6;
    const int rowBase = blockIdx.x * ROWS_PER_BLOCK + wv * ROWS_PER_WAVE;
    const int colStart = blockIdx.y * COLS_PER_CHUNK;
    const int lrow = lane & 15;   // A-row / B-col within 16
    const int kgrp = lane >> 4;   // 0..3
    const int koff = kgrp * 8;

    // A fragments for 2 row-tiles x 8 k-steps, held in registers all loop long
    bfrag a[2][8];
    #pragma unroll
    for (int t = 0; t < 2; ++t)
        #pragma unroll
        for (int ks = 0; ks < 8; ++ks)
            a[t][ks] = *reinterpret_cast<const bfrag*>(
                zn + (size_t)(rowBase + t * 16 + lrow) * DIM + ks * 32 + koff);

    float rowsum[2][4] = {{0.f, 0.f, 0.f, 0.f}, {0.f, 0.f, 0.f, 0.f}};
    const int rBaseInAcc = kgrp * 4;

    for (int ct = 0; ct < COLS_PER_CHUNK / 16; ++ct) {
        const int colBase = colStart + ct * 16;
        bfrag b[8];
        #pragma unroll
        for (int ks = 0; ks < 8; ++ks)
            b[ks] = *reinterpret_cast<const bfrag*>(
                zn + (size_t)(colBase + lrow) * DIM + ks * 32 + koff);
        facc acc0 = {0.f, 0.f, 0.f, 0.f}, acc1 = {0.f, 0.f, 0.f, 0.f};
        #pragma unroll
        for (int ks = 0; ks < 8; ++ks) {
            acc0 = __builtin_amdgcn_mfma_f32_16x16x32_bf16(a[0][ks], b[ks], acc0, 0, 0, 0);
            acc1 = __builtin_amdgcn_mfma_f32_16x16x32_bf16(a[1][ks], b[ks], acc1, 0, 0, 0);
        }
        #pragma unroll
        for (int t = 0; t < 2; ++t) {
            const facc acc = t ? acc1 : acc0;
            const int tRowBase = rowBase + t * 16;
            const bool diagTile = (colBase == tRowBase);
            const bool posTile  = (colBase == (tRowBase ^ HALF_B));
            #pragma unroll
            for (int j = 0; j < 4; ++j) {
                float s = acc[j] * 2.0f;              // / TEMPERATURE
                int rofs = rBaseInAcc + j;            // row within tile
                float e = __expf(s);
                if (diagTile && (lrow == rofs)) e = 0.0f;   // mask self
                rowsum[t][j] += e;
                if (posTile && (lrow == rofs)) pos[tRowBase + rofs] = s;
            }
        }
    }
    // reduce row sums across the 16 lanes of each kgrp group (they hold cols 0..15)
    #pragma unroll
    for (int t = 0; t < 2; ++t)
        #pragma unroll
        for (int j = 0; j < 4; ++j) {
            float v = rowsum[t][j];
            v += __shfl_xor(v, 1);
            v += __shfl_xor(v, 2);
            v += __shfl_xor(v, 4);
            v += __shfl_xor(v, 8);
            if (lrow == 0)
                partial[(size_t)blockIdx.y * N_TOT + rowBase + t * 16 + rBaseInAcc + j] = v;
        }
}

// Kernel 3: per-row lse - pos, block partial sums (deterministic)
__global__ __launch_bounds__(256) void lse_kernel(const float* __restrict__ partial,
                                                  const float* __restrict__ pos,
                                                  float* __restrict__ blockSums) {
    int r = blockIdx.x * 256 + threadIdx.x;
    float S = 0.0f;
    #pragma unroll
    for (int c = 0; c < CHUNKS; ++c) S += partial[(size_t)c * N_TOT + r];
    float v = logf(S) - pos[r];
    __shared__ float red[256];
    red[threadIdx.x] = v;
    __syncthreads();
    #pragma unroll
    for (int s = 128; s; s >>= 1) {
        if (threadIdx.x < s) red[threadIdx.x] += red[threadIdx.x + s];
        __syncthreads();
    }
    if (threadIdx.x == 0) blockSums[blockIdx.x] = red[0];
}

// Kernel 4: final reduce of 32 block sums -> loss
__global__ void final_kernel(const float* __restrict__ blockSums, float* __restrict__ out) {
    int lane = threadIdx.x;
    float v = (lane < 32) ? blockSums[lane] : 0.0f;
    #pragma unroll
    for (int off = 32; off; off >>= 1) v += __shfl_xor(v, off);
    if (lane == 0) out[0] = v / (float)N_TOT;
}

extern "C" void kernel_launch(void* const* d_in, const int* in_sizes, int n_in,
                              void* d_out, int out_size, void* d_ws, size_t ws_size,
                              hipStream_t stream) {
    const float* zi = (const float*)d_in[0];
    const float* zj = (const float*)d_in[1];
    char* ws = (char*)d_ws;

    unsigned short* zn = (unsigned short*)ws;                       // 4 MB
    float* pos        = (float*)(ws + (size_t)N_TOT * DIM * 2);     // 32 KB
    float* partial    = pos + N_TOT;                                // CHUNKS*N_TOT*4 = 512 KB
    float* blockSums  = partial + (size_t)CHUNKS * N_TOT;           // 128 B
    float* out        = (float*)d_out;

    norm_kernel<<<N_TOT / 4, 256, 0, stream>>>(zi, zj, zn);
    dim3 g2(ROW_BLOCKS, CHUNKS);
    sim_kernel<<<g2, 256, 0, stream>>>(zn, partial, pos);
    lse_kernel<<<N_TOT / 256, 256, 0, stream>>>(partial, pos, blockSums);
    final_kernel<<<1, 64, 0, stream>>>(blockSums, out);
}